// Round 4
// baseline (102.907 us; speedup 1.0000x reference)
//
#include <hip/hip_runtime.h>
#include <hip/hip_bf16.h>

// Nearest-neighbor 4D upsample (scale=2 on axes T,Z,Y,X).
// in : (2, 8, 8, 16, 64, 64)  f32  = 8,388,608 elems (33.5 MB)
// out: (2, 8, 16, 32, 128,128) f32 = 134,217,728 elems (537 MB)
//
// R3 A/B: identical to R2 but with PLAIN stores (no nontemporal hint).
// Rationale: input is read exactly once, so protecting L2 from the write
// stream buys nothing; the harness fill kernels (6.6-6.75 TB/s) use plain
// stores. Single-variable test of the nt flag.

typedef float f32x4 __attribute__((ext_vector_type(4)));
typedef float f32x2 __attribute__((ext_vector_type(2)));

__global__ __launch_bounds__(256) void UpsampleNearest4D_38912403701977_kernel(
    const float* __restrict__ in, f32x4* __restrict__ out) {
    unsigned j = blockIdx.x * 256u + threadIdx.x;   // [0, 4,194,304)

    // Decode INPUT coords. Per input row (64 x) there are 32 x-pairs.
    unsigned x4 = j & 31u;          // input x-pair index -> output quad x4
    unsigned r  = j >> 5;
    unsigned y  = r & 63u;  r >>= 6;   // y_in  [0,64)
    unsigned z  = r & 15u;  r >>= 4;   // z_in  [0,16)
    unsigned t  = r & 7u;              // t_in  [0,8)
    unsigned nc = r >> 3;              // n*c   [0,16)

    unsigned in_idx = ((((nc * 8u + t) * 16u + z) * 64u + y) * 64u) + (x4 << 1);
    f32x2 a = *reinterpret_cast<const f32x2*>(in + in_idx);  // 8B aligned
    f32x4 v = { a.x, a.x, a.y, a.y };

    // Output quad index: out dims (16, 16t, 32z, 128y, 128x) -> 32 quads/row.
    unsigned base = ((((nc * 16u + 2u * t) * 32u + 2u * z) * 128u + 2u * y) * 32u) + x4;
    const unsigned dy = 32u;              // +1 y row (in quads)
    const unsigned dz = 128u * 32u;       // +1 z plane
    const unsigned dt = 32u * 128u * 32u; // +1 t volume

    out[base]           = v;
    out[base + dy]      = v;
    out[base + dz]      = v;
    out[base + dz + dy] = v;
    out[base + dt]           = v;
    out[base + dt + dy]      = v;
    out[base + dt + dz]      = v;
    out[base + dt + dz + dy] = v;
}

extern "C" void kernel_launch(void* const* d_in, const int* in_sizes, int n_in,
                              void* d_out, int out_size, void* d_ws, size_t ws_size,
                              hipStream_t stream) {
    const float* in = (const float*)d_in[0];
    f32x4* out = (f32x4*)d_out;
    // 4,194,304 threads, one float2 -> 8 float4 stores each.
    dim3 block(256);
    dim3 grid(4194304u / 256u);   // 16384 blocks
    UpsampleNearest4D_38912403701977_kernel<<<grid, block, 0, stream>>>(in, out);
}